// Round 1
// baseline (88.589 us; speedup 1.0000x reference)
//
#include <hip/hip_runtime.h>
#include <hip/hip_bf16.h>

// Problem constants
#define BHALF 4096      // B = 8192/2
#define DDIM 128        // feature dim per matrix
#define KCAT 384        // 3*DDIM, packed row width
#define TEMP_INV 10.0f  // 1/TEMP

typedef __attribute__((ext_vector_type(8))) short short8;   // 8 bf16 (4 VGPRs)
typedef __attribute__((ext_vector_type(4))) float f32x4;    // MFMA accumulator

// ---------------------------------------------------------------------------
// Normalize rows of x,y,z (fp32, 8192x128 each) and write bf16 into packed
// layouts: nrm1[4096][384] = [x1|y1|z1], nrm2[4096][384] = [x2|y2|z2].
// One wave per row.
__global__ __launch_bounds__(256) void normalize_kernel(
    const float* __restrict__ x, const float* __restrict__ y,
    const float* __restrict__ z,
    ushort* __restrict__ nrm1, ushort* __restrict__ nrm2) {
  int wave = threadIdx.x >> 6;
  int lane = threadIdx.x & 63;
  int gr = blockIdx.x * 4 + wave;        // 0 .. 3*8192-1
  int mat = gr >> 13;                    // which matrix (0..2)
  int r = gr & 8191;                     // row within matrix
  const float* src = (mat == 0 ? x : (mat == 1 ? y : z)) + (size_t)r * DDIM;
  float2 v = *(const float2*)(src + lane * 2);
  float s = v.x * v.x + v.y * v.y;
#pragma unroll
  for (int m = 1; m < 64; m <<= 1) s += __shfl_xor(s, m, 64);
  float scale = 1.0f / fmaxf(sqrtf(s), 1e-12f);
  ushort* dst = (r < BHALF ? nrm1 + (size_t)r * KCAT
                           : nrm2 + (size_t)(r - BHALF) * KCAT)
                + mat * DDIM + lane * 2;
  __hip_bfloat162 o;
  o.x = __float2bfloat16(v.x * scale);
  o.y = __float2bfloat16(v.y * scale);
  *(__hip_bfloat162*)dst = o;
}

// ---------------------------------------------------------------------------
// Per-row diagonal dots in fp32 straight from raw inputs:
// dxyz[m*4096 + i] = dot(m1_i/||m1_i||, m2_i/||m2_i||)
__global__ __launch_bounds__(256) void diag_kernel(
    const float* __restrict__ x, const float* __restrict__ y,
    const float* __restrict__ z, float* __restrict__ dxyz) {
  int wave = threadIdx.x >> 6;
  int lane = threadIdx.x & 63;
  int i = blockIdx.x * 4 + wave;  // 0..4095
  const float* mats[3] = {x, y, z};
#pragma unroll
  for (int m = 0; m < 3; ++m) {
    const float* p1 = mats[m] + (size_t)i * DDIM;
    const float* p2 = mats[m] + (size_t)(i + BHALF) * DDIM;
    float2 a = *(const float2*)(p1 + lane * 2);
    float2 b = *(const float2*)(p2 + lane * 2);
    float s1 = a.x * a.x + a.y * a.y;
    float s2 = b.x * b.x + b.y * b.y;
    float d = a.x * b.x + a.y * b.y;
#pragma unroll
    for (int mm = 1; mm < 64; mm <<= 1) {
      s1 += __shfl_xor(s1, mm, 64);
      s2 += __shfl_xor(s2, mm, 64);
      d += __shfl_xor(d, mm, 64);
    }
    if (lane == 0)
      dxyz[m * BHALF + i] =
          d / (fmaxf(sqrtf(s1), 1e-12f) * fmaxf(sqrtf(s2), 1e-12f));
  }
}

// ---------------------------------------------------------------------------
// Fused gram kernel: per blockIdx.z gram g, compute 128x128 tile of
// A @ B^T (A,B are row panels of the packed bf16 buffers), apply
// exp(val/TEMP), reduce row sums and col sums, atomicAdd into `sums`.
// sums layout (4096 floats each): [rs0, cs0, rs1, cs1, rs2, cs2, rs3]
//   g0: x1@y1^T  g1: x1@z1^T  g2: y1@z1^T  g3: xyz1@xyz2^T (rowsum only)
__global__ __launch_bounds__(256) void gram_kernel(
    const ushort* __restrict__ nrm1, const ushort* __restrict__ nrm2,
    float* __restrict__ sums) {
  int g = blockIdx.z;
  const ushort* Abase;
  const ushort* Bbase;
  int K;
  float* rs;
  float* cs;
  if (g == 0) {
    Abase = nrm1; Bbase = nrm1 + 128; K = 128;
    rs = sums; cs = sums + 4096;
  } else if (g == 1) {
    Abase = nrm1; Bbase = nrm1 + 256; K = 128;
    rs = sums + 2 * 4096; cs = sums + 3 * 4096;
  } else if (g == 2) {
    Abase = nrm1 + 128; Bbase = nrm1 + 256; K = 128;
    rs = sums + 4 * 4096; cs = sums + 5 * 4096;
  } else {
    Abase = nrm1; Bbase = nrm2; K = 384;
    rs = sums + 6 * 4096; cs = nullptr;
  }

  __shared__ ushort As[128][40];  // +8 pad -> 80B row stride, <=2-way banks
  __shared__ ushort Bs[128][40];

  int tid = threadIdx.x;
  int lane = tid & 63;
  int wave = tid >> 6;
  int wr = wave >> 1;  // wave row (0..1), owns 64 rows
  int wc = wave & 1;   // wave col (0..1), owns 64 cols

  int rowbase = blockIdx.x * 128;
  int colbase = blockIdx.y * 128;

  f32x4 acc[4][4] = {};

  for (int k0 = 0; k0 < K; k0 += 32) {
    __syncthreads();
#pragma unroll
    for (int it = 0; it < 2; ++it) {
      int idx = tid + it * 256;
      int row = idx >> 2;
      int chunk = idx & 3;
      *(uint4*)&As[row][chunk * 8] =
          *(const uint4*)(Abase + (size_t)(rowbase + row) * KCAT + k0 + chunk * 8);
      *(uint4*)&Bs[row][chunk * 8] =
          *(const uint4*)(Bbase + (size_t)(colbase + row) * KCAT + k0 + chunk * 8);
    }
    __syncthreads();
    short8 af[4], bf[4];
    int rsel = lane & 15;
    int ksel = (lane >> 4) * 8;
#pragma unroll
    for (int m = 0; m < 4; ++m)
      af[m] = *(const short8*)&As[wr * 64 + m * 16 + rsel][ksel];
#pragma unroll
    for (int n = 0; n < 4; ++n)
      bf[n] = *(const short8*)&Bs[wc * 64 + n * 16 + rsel][ksel];
#pragma unroll
    for (int m = 0; m < 4; ++m)
#pragma unroll
      for (int n = 0; n < 4; ++n)
        acc[m][n] = __builtin_amdgcn_mfma_f32_16x16x32_bf16(af[m], bf[n],
                                                            acc[m][n], 0, 0, 0);
  }

  // epilogue: exp in-place
#pragma unroll
  for (int m = 0; m < 4; ++m)
#pragma unroll
    for (int n = 0; n < 4; ++n)
#pragma unroll
      for (int r = 0; r < 4; ++r)
        acc[m][n][r] = __expf(acc[m][n][r] * TEMP_INV);

  // row sums: C/D frag layout col = lane&15, row = (lane>>4)*4 + r
#pragma unroll
  for (int m = 0; m < 4; ++m) {
    float rsum[4];
#pragma unroll
    for (int r = 0; r < 4; ++r)
      rsum[r] = acc[m][0][r] + acc[m][1][r] + acc[m][2][r] + acc[m][3][r];
#pragma unroll
    for (int r = 0; r < 4; ++r) {
      rsum[r] += __shfl_xor(rsum[r], 1, 64);
      rsum[r] += __shfl_xor(rsum[r], 2, 64);
      rsum[r] += __shfl_xor(rsum[r], 4, 64);
      rsum[r] += __shfl_xor(rsum[r], 8, 64);
    }
    if ((lane & 15) == 0) {
      int rbase = rowbase + wr * 64 + m * 16 + (lane >> 4) * 4;
#pragma unroll
      for (int r = 0; r < 4; ++r) atomicAdd(&rs[rbase + r], rsum[r]);
    }
  }

  // col sums (skip for the view gram)
  if (cs != nullptr) {
#pragma unroll
    for (int n = 0; n < 4; ++n) {
      float csum = 0.0f;
#pragma unroll
      for (int m = 0; m < 4; ++m)
#pragma unroll
        for (int r = 0; r < 4; ++r) csum += acc[m][n][r];
      csum += __shfl_xor(csum, 16, 64);
      csum += __shfl_xor(csum, 32, 64);
      if (lane < 16) atomicAdd(&cs[colbase + wc * 64 + n * 16 + lane], csum);
    }
  }
}

// ---------------------------------------------------------------------------
// Final scalar reduction.
__global__ __launch_bounds__(256) void loss_kernel(
    const float* __restrict__ sums, const float* __restrict__ dxyz,
    float* __restrict__ out) {
  const float* rs0 = sums;
  const float* cs0 = sums + 4096;
  const float* rs1 = sums + 2 * 4096;
  const float* cs1 = sums + 3 * 4096;
  const float* rs2 = sums + 4 * 4096;
  const float* cs2 = sums + 5 * 4096;
  const float* rs3 = sums + 6 * 4096;
  const float* dx = dxyz;
  const float* dy = dxyz + 4096;
  const float* dz = dxyz + 2 * 4096;
  float acc = 0.0f;
  for (int i = threadIdx.x; i < BHALF; i += 256) {
    float lx = logf(rs0[i] + rs1[i]) - TEMP_INV * dx[i];
    float ly = logf(cs0[i] + rs2[i]) - TEMP_INV * dy[i];
    float lz = logf(cs1[i] + cs2[i]) - TEMP_INV * dz[i];
    float lv = logf(rs3[i]) - TEMP_INV * (dx[i] + dy[i] + dz[i]);
    acc += lx + ly + lz + lv;
  }
  __shared__ float red[4];
#pragma unroll
  for (int m = 1; m < 64; m <<= 1) acc += __shfl_xor(acc, m, 64);
  if ((threadIdx.x & 63) == 0) red[threadIdx.x >> 6] = acc;
  __syncthreads();
  if (threadIdx.x == 0)
    out[0] = (red[0] + red[1] + red[2] + red[3]) * (1.0f / 4096.0f);
}

// ---------------------------------------------------------------------------
extern "C" void kernel_launch(void* const* d_in, const int* in_sizes, int n_in,
                              void* d_out, int out_size, void* d_ws,
                              size_t ws_size, hipStream_t stream) {
  const float* x = (const float*)d_in[0];
  const float* y = (const float*)d_in[1];
  const float* z = (const float*)d_in[2];
  char* ws = (char*)d_ws;
  ushort* nrm1 = (ushort*)ws;                       // 4096*384 bf16
  ushort* nrm2 = nrm1 + (size_t)BHALF * KCAT;       // 4096*384 bf16
  float* sums = (float*)(ws + 2 * (size_t)BHALF * KCAT * sizeof(ushort));
  float* dxyz = sums + 7 * 4096;                    // 3*4096 fp32

  hipMemsetAsync(sums, 0, 7 * 4096 * sizeof(float), stream);
  normalize_kernel<<<3 * 8192 / 4, 256, 0, stream>>>(x, y, z, nrm1, nrm2);
  diag_kernel<<<BHALF / 4, 256, 0, stream>>>(x, y, z, dxyz);
  gram_kernel<<<dim3(32, 32, 4), 256, 0, stream>>>(nrm1, nrm2, sums);
  loss_kernel<<<1, 256, 0, stream>>>(sums, dxyz, (float*)d_out);
}

// Round 2
// 77.468 us; speedup vs baseline: 1.1435x; 1.1435x over previous
//
#include <hip/hip_runtime.h>
#include <hip/hip_bf16.h>

// Problem constants
#define BHALF 4096      // B = 8192/2
#define DDIM 128        // feature dim per matrix
#define KCAT 384        // 3*DDIM, packed row width
#define TEMP_INV 10.0f  // 1/TEMP

typedef __attribute__((ext_vector_type(8))) short short8;   // 8 bf16 (4 VGPRs)
typedef __attribute__((ext_vector_type(4))) float f32x4;    // MFMA accumulator

// Async global->LDS, 16B per lane. LDS dest must be wave-uniform (HW adds
// lane*16). Global source is per-lane.
__device__ __forceinline__ void gload16(const ushort* g, ushort* l) {
  __builtin_amdgcn_global_load_lds(
      (const __attribute__((address_space(1))) unsigned int*)g,
      (__attribute__((address_space(3))) unsigned int*)l, 16, 0, 0);
}

// ---------------------------------------------------------------------------
// Fused normalize + diag: one wave per (matrix, row-pair i).
// Writes bf16 normalized rows into packed nrm1[4096][384]=[x1|y1|z1],
// nrm2[4096][384]=[x2|y2|z2], and dxyz[m*4096+i] = dot(m1_i_hat, m2_i_hat).
__global__ __launch_bounds__(256) void norm_diag_kernel(
    const float* __restrict__ x, const float* __restrict__ y,
    const float* __restrict__ z, ushort* __restrict__ nrm1,
    ushort* __restrict__ nrm2, float* __restrict__ dxyz) {
  int wave = threadIdx.x >> 6;
  int lane = threadIdx.x & 63;
  int gi = blockIdx.x * 4 + wave;  // 0 .. 3*4096-1
  int mat = gi >> 12;
  int i = gi & 4095;
  const float* src = (mat == 0 ? x : (mat == 1 ? y : z));
  float2 a = *(const float2*)(src + (size_t)i * DDIM + lane * 2);
  float2 b = *(const float2*)(src + (size_t)(i + BHALF) * DDIM + lane * 2);
  float s1 = a.x * a.x + a.y * a.y;
  float s2 = b.x * b.x + b.y * b.y;
  float d = a.x * b.x + a.y * b.y;
#pragma unroll
  for (int m = 1; m < 64; m <<= 1) {
    s1 += __shfl_xor(s1, m, 64);
    s2 += __shfl_xor(s2, m, 64);
    d += __shfl_xor(d, m, 64);
  }
  float r1 = 1.0f / fmaxf(sqrtf(s1), 1e-12f);
  float r2 = 1.0f / fmaxf(sqrtf(s2), 1e-12f);
  ushort* d1 = nrm1 + (size_t)i * KCAT + mat * DDIM + lane * 2;
  ushort* d2 = nrm2 + (size_t)i * KCAT + mat * DDIM + lane * 2;
  __hip_bfloat162 o1, o2;
  o1.x = __float2bfloat16(a.x * r1);
  o1.y = __float2bfloat16(a.y * r1);
  o2.x = __float2bfloat16(b.x * r2);
  o2.y = __float2bfloat16(b.y * r2);
  *(__hip_bfloat162*)d1 = o1;
  *(__hip_bfloat162*)d2 = o2;
  if (lane == 0) dxyz[mat * BHALF + i] = d * r1 * r2;
}

// ---------------------------------------------------------------------------
// Fused gram kernel (m97 structure): 128x128 tile, 4 waves x (64x64),
// global_load_lds(16B) staging into linear LDS [128][32] with chunk swizzle
// (source pre-swizzled, read XOR'd back — involution chunk ^= (row>>1)&3).
// Epilogue: exp(v/T), row-sum + col-sum atomics.
// sums layout (4096 floats each): [rs0, cs0, rs1, cs1, rs2, cs2, rs3]
//   g0: x1@y1^T  g1: x1@z1^T  g2: y1@z1^T  g3: xyz1@xyz2^T (rowsum only)
__global__ __launch_bounds__(256) void gram_kernel(
    const ushort* __restrict__ nrm1, const ushort* __restrict__ nrm2,
    float* __restrict__ sums) {
  int g = blockIdx.z;
  const ushort* Abase;
  const ushort* Bbase;
  int K;
  float* rs;
  float* cs;
  if (g == 0) {
    Abase = nrm1; Bbase = nrm1 + 128; K = 128;
    rs = sums; cs = sums + 4096;
  } else if (g == 1) {
    Abase = nrm1; Bbase = nrm1 + 256; K = 128;
    rs = sums + 2 * 4096; cs = sums + 3 * 4096;
  } else if (g == 2) {
    Abase = nrm1 + 128; Bbase = nrm1 + 256; K = 128;
    rs = sums + 4 * 4096; cs = sums + 5 * 4096;
  } else {
    Abase = nrm1; Bbase = nrm2; K = 384;
    rs = sums + 6 * 4096; cs = nullptr;
  }

  __shared__ ushort As[128][32];  // linear: required by global_load_lds
  __shared__ ushort Bs[128][32];

  int tid = threadIdx.x;
  int lane = tid & 63;
  int wave = tid >> 6;
  int wr = wave >> 1;  // wave row (0..1), owns 64 rows
  int wc = wave & 1;   // wave col (0..1), owns 64 cols

  int rowbase = blockIdx.x * 128;
  int colbase = blockIdx.y * 128;

  // Staging addressing: wave w instruction i covers LDS rows [(w + i*4)*16).
  // Lane l -> row r0 + (l>>2), 16B chunk (l&3). Source chunk pre-swizzled by
  // ((lrow>>1)&3) so swizzled reads below recover linear data.
  int lrow = lane >> 2;
  int lchunk8 = (((lane & 3) ^ ((lrow >> 1) & 3)) << 3);
  const ushort* gA0 =
      Abase + (size_t)(rowbase + wave * 16 + lrow) * KCAT + lchunk8;
  const ushort* gA1 = gA0 + (size_t)64 * KCAT;
  const ushort* gB0 =
      Bbase + (size_t)(colbase + wave * 16 + lrow) * KCAT + lchunk8;
  const ushort* gB1 = gB0 + (size_t)64 * KCAT;
  ushort* lA0 = &As[wave * 16][0];
  ushort* lA1 = &As[wave * 16 + 64][0];
  ushort* lB0 = &Bs[wave * 16][0];
  ushort* lB1 = &Bs[wave * 16 + 64][0];

  // Fragment read addressing (swizzled slot; uniform across m since
  // (row>>1)&3 only depends on rsel)
  int rsel = lane & 15;
  int slot8 = (((lane >> 4) ^ ((rsel >> 1) & 3)) << 3);

  f32x4 acc[4][4] = {};

  int ksteps = K >> 5;
  for (int ks = 0; ks < ksteps; ++ks) {
    gload16(gA0, lA0);
    gload16(gA1, lA1);
    gload16(gB0, lB0);
    gload16(gB1, lB1);
    gA0 += 32; gA1 += 32; gB0 += 32; gB1 += 32;
    __syncthreads();  // drains vmcnt: staged tile visible
    short8 af[4], bf[4];
#pragma unroll
    for (int m = 0; m < 4; ++m)
      af[m] = *(const short8*)&As[wr * 64 + m * 16 + rsel][slot8];
#pragma unroll
    for (int n = 0; n < 4; ++n)
      bf[n] = *(const short8*)&Bs[wc * 64 + n * 16 + rsel][slot8];
#pragma unroll
    for (int m = 0; m < 4; ++m)
#pragma unroll
      for (int n = 0; n < 4; ++n)
        acc[m][n] = __builtin_amdgcn_mfma_f32_16x16x32_bf16(af[m], bf[n],
                                                            acc[m][n], 0, 0, 0);
    __syncthreads();  // all reads done before next stage overwrites
  }

  // epilogue: exp in-place
#pragma unroll
  for (int m = 0; m < 4; ++m)
#pragma unroll
    for (int n = 0; n < 4; ++n)
#pragma unroll
      for (int r = 0; r < 4; ++r)
        acc[m][n][r] = __expf(acc[m][n][r] * TEMP_INV);

  // row sums: C/D frag layout col = lane&15, row = (lane>>4)*4 + r
#pragma unroll
  for (int m = 0; m < 4; ++m) {
    float rsum[4];
#pragma unroll
    for (int r = 0; r < 4; ++r)
      rsum[r] = acc[m][0][r] + acc[m][1][r] + acc[m][2][r] + acc[m][3][r];
#pragma unroll
    for (int r = 0; r < 4; ++r) {
      rsum[r] += __shfl_xor(rsum[r], 1, 64);
      rsum[r] += __shfl_xor(rsum[r], 2, 64);
      rsum[r] += __shfl_xor(rsum[r], 4, 64);
      rsum[r] += __shfl_xor(rsum[r], 8, 64);
    }
    if ((lane & 15) == 0) {
      int rbase = rowbase + wr * 64 + m * 16 + (lane >> 4) * 4;
#pragma unroll
      for (int r = 0; r < 4; ++r) atomicAdd(&rs[rbase + r], rsum[r]);
    }
  }

  // col sums (skip for the view gram)
  if (cs != nullptr) {
#pragma unroll
    for (int n = 0; n < 4; ++n) {
      float csum = 0.0f;
#pragma unroll
      for (int m = 0; m < 4; ++m)
#pragma unroll
        for (int r = 0; r < 4; ++r) csum += acc[m][n][r];
      csum += __shfl_xor(csum, 16, 64);
      csum += __shfl_xor(csum, 32, 64);
      if (lane < 16) atomicAdd(&cs[colbase + wc * 64 + n * 16 + lane], csum);
    }
  }
}

// ---------------------------------------------------------------------------
// Final scalar reduction.
__global__ __launch_bounds__(1024) void loss_kernel(
    const float* __restrict__ sums, const float* __restrict__ dxyz,
    float* __restrict__ out) {
  const float* rs0 = sums;
  const float* cs0 = sums + 4096;
  const float* rs1 = sums + 2 * 4096;
  const float* cs1 = sums + 3 * 4096;
  const float* rs2 = sums + 4 * 4096;
  const float* cs2 = sums + 5 * 4096;
  const float* rs3 = sums + 6 * 4096;
  int tid = threadIdx.x;
  float acc = 0.0f;
  for (int i = tid; i < BHALF; i += 1024) {
    float dxv = dxyz[i];
    float dyv = dxyz[4096 + i];
    float dzv = dxyz[2 * 4096 + i];
    float lx = logf(rs0[i] + rs1[i]) - TEMP_INV * dxv;
    float ly = logf(cs0[i] + rs2[i]) - TEMP_INV * dyv;
    float lz = logf(cs1[i] + cs2[i]) - TEMP_INV * dzv;
    float lv = logf(rs3[i]) - TEMP_INV * (dxv + dyv + dzv);
    acc += lx + ly + lz + lv;
  }
  __shared__ float red[16];
#pragma unroll
  for (int m = 1; m < 64; m <<= 1) acc += __shfl_xor(acc, m, 64);
  if ((tid & 63) == 0) red[tid >> 6] = acc;
  __syncthreads();
  if (tid == 0) {
    float t = 0.0f;
#pragma unroll
    for (int i = 0; i < 16; ++i) t += red[i];
    out[0] = t * (1.0f / 4096.0f);
  }
}

// ---------------------------------------------------------------------------
extern "C" void kernel_launch(void* const* d_in, const int* in_sizes, int n_in,
                              void* d_out, int out_size, void* d_ws,
                              size_t ws_size, hipStream_t stream) {
  const float* x = (const float*)d_in[0];
  const float* y = (const float*)d_in[1];
  const float* z = (const float*)d_in[2];
  char* ws = (char*)d_ws;
  ushort* nrm1 = (ushort*)ws;                       // 4096*384 bf16
  ushort* nrm2 = nrm1 + (size_t)BHALF * KCAT;       // 4096*384 bf16
  float* sums = (float*)(ws + 2 * (size_t)BHALF * KCAT * sizeof(ushort));
  float* dxyz = sums + 7 * 4096;                    // 3*4096 fp32

  hipMemsetAsync(sums, 0, 7 * 4096 * sizeof(float), stream);
  norm_diag_kernel<<<3 * BHALF / 4, 256, 0, stream>>>(x, y, z, nrm1, nrm2,
                                                      dxyz);
  gram_kernel<<<dim3(32, 32, 4), 256, 0, stream>>>(nrm1, nrm2, sums);
  loss_kernel<<<1, 1024, 0, stream>>>(sums, dxyz, (float*)d_out);
}